// Round 5
// baseline (260.791 us; speedup 1.0000x reference)
//
#include <hip/hip_runtime.h>
#include <hip/hip_bf16.h>

#define NPTS 2048
#define NOVER 6144
#define STEP1 1536
#define STEP2 512
#define HW_TOT 262144

__device__ __forceinline__ float prelu_f(float x, float a) { return x >= 0.0f ? x : a * x; }

// coarse (128x128) bilinear coords for 512-output half-pixel sampling
__device__ __forceinline__ void coarse_coords(int h, int w, float& fy, float& fx,
                                              int& y0, int& y1, int& x0, int& x1) {
  float sy = (h + 0.5f) * 0.25f - 0.5f;
  float sx = (w + 0.5f) * 0.25f - 0.5f;
  float yf = floorf(sy), xf = floorf(sx);
  fy = sy - yf; fx = sx - xf;
  int yi = (int)yf, xi = (int)xf;
  y0 = min(127, max(0, yi)); y1 = min(127, max(0, yi + 1));
  x0 = min(127, max(0, xi)); x1 = min(127, max(0, xi + 1));
}

__device__ __forceinline__ float coarse_sample(const float* __restrict__ ch, float fy, float fx,
                                               int y0, int y1, int x0, int x1) {
  float v00 = ch[(y0 << 7) + x0];
  float v01 = ch[(y0 << 7) + x1];
  float v10 = ch[(y1 << 7) + x0];
  float v11 = ch[(y1 << 7) + x1];
  return (1.0f - fy) * ((1.0f - fx) * v00 + fx * v01) + fy * ((1.0f - fx) * v10 + fx * v11);
}

// zero the f32 mask region (2*512*512 floats = 2 MB) -> 131072 uint4 stores
__global__ __launch_bounds__(256) void pr_fill_v5(uint4* __restrict__ p) {
  p[blockIdx.x * 256 + threadIdx.x] = make_uint4(0u, 0u, 0u, 0u);
}

// transpose w1 (256x259) -> wT1 (259x256), w2 (128x259) -> wT2 (259x128)
__global__ __launch_bounds__(256) void pr_wprep_v5(const float* __restrict__ w1,
                                                   const float* __restrict__ w2,
                                                   float* __restrict__ wT1,
                                                   float* __restrict__ wT2) {
  int gid = blockIdx.x * 256 + threadIdx.x;
  if (gid < 259 * 256) {
    int c = gid >> 8, o = gid & 255;
    wT1[c * 256 + o] = w1[o * 259 + c];
  } else {
    int g2 = gid - 259 * 256;
    if (g2 < 259 * 128) {
      int c = g2 >> 7, o = g2 & 127;
      wT2[c * 128 + o] = w2[o * 259 + c];
    }
  }
}

// uncertainty keys for 2*6144 candidates (monotone u32 encoding of u in (0,1])
__global__ __launch_bounds__(256) void pr_uncert_v5(const float* __restrict__ coarse,
                                                    const int* __restrict__ ridx,
                                                    unsigned* __restrict__ keys) {
  int gid = blockIdx.x * 256 + threadIdx.x;
  if (gid >= 2 * NOVER) return;
  int b = gid / NOVER, i = gid - b * NOVER;
  int lin = ridx[i];
  int h = lin >> 9, w = lin & 511;
  float fy, fx; int y0, y1, x0, x1;
  coarse_coords(h, w, fy, fx, y0, y1, x0, x1);
  const float* cb = coarse + (((size_t)b * 3) << 14);
  float p0 = coarse_sample(cb, fy, fx, y0, y1, x0, x1);
  float p1 = coarse_sample(cb + (1 << 14), fy, fx, y0, y1, x0, x1);
  float p2 = coarse_sample(cb + (2 << 14), fy, fx, y0, y1, x0, x1);
  float m = fmaxf(p0, fmaxf(p1, p2));
  float e0 = expf(p0 - m), e1 = expf(p1 - m), e2 = expf(p2 - m);
  float s = e0 + e1 + e2;
  float q0 = e0 / s, q1 = e1 / s, q2 = e2 / s;
  float a0 = q0, a1 = q1, a2 = q2, tmp;
  if (a0 < a1) { tmp = a0; a0 = a1; a1 = tmp; }
  if (a1 < a2) { tmp = a1; a1 = a2; a2 = tmp; }
  if (a0 < a1) { tmp = a0; a0 = a1; a1 = tmp; }
  float u = 1.0f - (a0 - a1);   // strictly positive -> bit pattern is order-monotone
  keys[gid] = __float_as_uint(u);
}

// One block per batch: exact radix-select top-1536 (val desc, idx asc tie-break),
// mask scatter, and bitmap-based ascending sort of the 2048 selected lins.
__global__ __launch_bounds__(1024) void pr_topk_v5(const unsigned* __restrict__ keys,
                                                   const int* __restrict__ ridx,
                                                   int* __restrict__ lin_sorted,
                                                   float* __restrict__ mask) {
  __shared__ unsigned kv[NOVER];            // 24 KB
  __shared__ unsigned bitmap[8192];         // 32 KB (262144 bits)
  __shared__ unsigned hist[256];
  __shared__ unsigned short tiebuf[NOVER];  // 12 KB (worst-case ties)
  __shared__ unsigned scanbuf[16];
  __shared__ unsigned selinfo[2];           // [0]=prefix/T, [1]=R
  __shared__ int tiecnt;
  const int b = blockIdx.x, t = threadIdx.x;
  const int lane = t & 63, wid = t >> 6;

  for (int i = t; i < NOVER; i += 1024) kv[i] = keys[b * NOVER + i];
  for (int i = t; i < 8192; i += 1024) bitmap[i] = 0u;
  if (t == 0) { selinfo[1] = STEP1; tiecnt = 0; }
  __syncthreads();

  // 4-pass radix select (descending): find exact threshold T and tie-rank r
  unsigned prefix = 0u;
  for (int pass = 0; pass < 4; ++pass) {
    const int shift = 24 - 8 * pass;
    const unsigned maskHi = (pass == 0) ? 0u : (0xFFFFFFFFu << (shift + 8));
    for (int i = t; i < 256; i += 1024) hist[i] = 0u;
    __syncthreads();
    for (int i = t; i < NOVER; i += 1024) {
      unsigned k = kv[i];
      if ((k & maskHi) == prefix) atomicAdd(&hist[(k >> shift) & 255u], 1u);
    }
    __syncthreads();
    if (t < 64) {  // one wave: suffix scan over 256 bins (4 bins/lane)
      unsigned h0 = hist[t * 4], h1 = hist[t * 4 + 1], h2 = hist[t * 4 + 2], h3 = hist[t * 4 + 3];
      unsigned q = h0 + h1 + h2 + h3;
      unsigned s = q;
      for (int off = 1; off < 64; off <<= 1) {
        unsigned n = __shfl_down(s, off);
        if (t + off < 64) s += n;
      }
      unsigned exq = s - q;                    // count in strictly-higher quads
      unsigned R = selinfo[1];                 // lockstep: all lanes read before any write
      unsigned se3 = exq, se2 = se3 + h3, se1 = se2 + h2, se0 = se1 + h1;
      if (se3 < R && R <= se3 + h3)      { selinfo[0] = prefix | ((unsigned)(t * 4 + 3) << shift); selinfo[1] = R - se3; }
      else if (se2 < R && R <= se2 + h2) { selinfo[0] = prefix | ((unsigned)(t * 4 + 2) << shift); selinfo[1] = R - se2; }
      else if (se1 < R && R <= se1 + h1) { selinfo[0] = prefix | ((unsigned)(t * 4 + 1) << shift); selinfo[1] = R - se1; }
      else if (se0 < R && R <= se0 + h0) { selinfo[0] = prefix | ((unsigned)(t * 4 + 0) << shift); selinfo[1] = R - se0; }
    }
    __syncthreads();
    prefix = selinfo[0];
  }
  const unsigned T = prefix;
  const int r = (int)selinfo[1];   // take r smallest-index items among key==T

  // selection pass: key > T definitely in; ties collected
  for (int i = t; i < NOVER; i += 1024) {
    unsigned k = kv[i];
    if (k > T) {
      int lin = ridx[i];
      mask[(size_t)b * HW_TOT + lin] = 1.0f;
      atomicOr(&bitmap[lin >> 5], 1u << (lin & 31));
    } else if (k == T) {
      int pos = atomicAdd(&tiecnt, 1);
      tiebuf[pos] = (unsigned short)i;
    }
  }
  // coverage points (last 512 of the permutation; disjoint from candidates)
  for (int i = t; i < STEP2; i += 1024) {
    int lin = ridx[HW_TOT - STEP2 + i];
    mask[(size_t)b * HW_TOT + lin] = 1.0f;
    atomicOr(&bitmap[lin >> 5], 1u << (lin & 31));
  }
  __syncthreads();
  const int m = tiecnt;
  for (int j = t; j < m; j += 1024) {
    int idx = tiebuf[j];
    int rank = 0;
    for (int jj = 0; jj < m; ++jj) rank += (tiebuf[jj] < idx) ? 1 : 0;
    if (rank < r) {
      int lin = ridx[idx];
      mask[(size_t)b * HW_TOT + lin] = 1.0f;
      atomicOr(&bitmap[lin >> 5], 1u << (lin & 31));
    }
  }
  __syncthreads();

  // bitmap -> ascending lin_sorted via popcount prefix scan (2048 set bits exactly)
  unsigned mySum = 0;
#pragma unroll
  for (int q = 0; q < 8; ++q) mySum += __popc(bitmap[t * 8 + q]);
  unsigned v = mySum;
  for (int off = 1; off < 64; off <<= 1) {
    unsigned n = __shfl_up(v, off);
    if (lane >= off) v += n;
  }
  if (lane == 63) scanbuf[wid] = v;
  __syncthreads();
  if (t == 0) {
    unsigned run = 0;
    for (int w16 = 0; w16 < 16; ++w16) { unsigned tmp = scanbuf[w16]; scanbuf[w16] = run; run += tmp; }
  }
  __syncthreads();
  unsigned pos = (v - mySum) + scanbuf[wid];
  for (int q = 0; q < 8; ++q) {
    unsigned word = bitmap[t * 8 + q];
    int basebit = (t * 8 + q) << 5;
    while (word) {
      int bit = __ffs(word) - 1;
      word &= word - 1;
      lin_sorted[b * NPTS + pos++] = basebit + bit;
    }
  }
}

// Materialize featflat[g*259+c] (reference's flatten-concat-reshape layout) into ws.
// One block per point-group g (4096 blocks); writes coalesced; ~1M threads hide
// the scattered 64B-granular fine-plane corner reads.
__global__ __launch_bounds__(256) void pr_gather_v5(const float* __restrict__ fine,
                                                    const float* __restrict__ coarse,
                                                    const int* __restrict__ lin_sorted,
                                                    float* __restrict__ feat) {
  const int g = blockIdx.x;
  for (int c = threadIdx.x; c < 259; c += 256) {
    int j = g * 259 + c;
    float v;
    if (j < 1048576) {
      int nsrc = j >> 8, ch = j & 255;
      int bs = nsrc >> 11;
      int lin = lin_sorted[nsrc];
      int h = lin >> 9, w = lin & 511;
      float sy = (h + 0.5f) * 0.5f - 0.5f;
      float sx = (w + 0.5f) * 0.5f - 0.5f;
      float yf = floorf(sy), xf = floorf(sx);
      float fy = sy - yf, fx = sx - xf;
      int yi = (int)yf, xi = (int)xf;
      int y0 = min(255, max(0, yi)), y1 = min(255, max(0, yi + 1));
      int x0 = min(255, max(0, xi)), x1 = min(255, max(0, xi + 1));
      const float* base = fine + (((size_t)(bs * 256 + ch)) << 16);
      float v00 = base[(y0 << 8) + x0];
      float v01 = base[(y0 << 8) + x1];
      float v10 = base[(y1 << 8) + x0];
      float v11 = base[(y1 << 8) + x1];
      v = (1.0f - fy) * ((1.0f - fx) * v00 + fx * v01) + fy * ((1.0f - fx) * v10 + fx * v11);
    } else {
      int jj = j - 1048576;
      int nsrc = jj / 3;
      int kk = jj - nsrc * 3;
      int bs = nsrc >> 11;
      int lin = lin_sorted[nsrc];
      int h = lin >> 9, w = lin & 511;
      float fy, fx; int y0, y1, x0, x1;
      coarse_coords(h, w, fy, fx, y0, y1, x0, x1);
      v = coarse_sample(coarse + (((size_t)bs * 3 + kk) << 14), fy, fx, y0, y1, x0, x1);
    }
    feat[j] = v;
  }
}

// 3-layer MLP over 16 points/block; feat pre-gathered -> LDS fill is one
// contiguous coalesced stream (xs[c][p] = feat[g0*259 + (p*259+c)]).
__global__ __launch_bounds__(256) void pr_mlp_v5(const float* __restrict__ feat,
                                                 const float* __restrict__ wT1,
                                                 const float* __restrict__ wT2,
                                                 const float* __restrict__ w3,
                                                 const float* __restrict__ pa,
                                                 float* __restrict__ out) {
  __shared__ __align__(16) float xs[259][16];
  __shared__ __align__(16) float l1t[256][16];
  __shared__ __align__(16) float l2t[128][16];
  const int t = threadIdx.x;
  const int g0 = blockIdx.x * 16;
  const float a = pa[0];

  // contiguous coalesced LDS fill: i enumerates p*259+c
  const float* fb = feat + g0 * 259;
  for (int i = t; i < 16 * 259; i += 256) {
    int p = i / 259;
    int c = i - p * 259;
    xs[c][p] = fb[i];
  }
  __syncthreads();

  // layer 1: 259 -> 256; thread = 4 outs (lane-quad, coalesced weights) x 4 points
  {
    const int ob = (t & 63) * 4;
    const int pb = (t >> 6) * 4;
    float acc[4][4];
#pragma unroll
    for (int i = 0; i < 4; ++i)
#pragma unroll
      for (int q = 0; q < 4; ++q) acc[i][q] = 0.0f;
    for (int c = 0; c < 259; ++c) {
      const float4 wv = *(const float4*)&wT1[c * 256 + ob];   // 64 lanes -> 1 KB contiguous
      const float4 xv = *(const float4*)&xs[c][pb];           // wave-uniform broadcast
      acc[0][0] = fmaf(wv.x, xv.x, acc[0][0]); acc[0][1] = fmaf(wv.x, xv.y, acc[0][1]);
      acc[0][2] = fmaf(wv.x, xv.z, acc[0][2]); acc[0][3] = fmaf(wv.x, xv.w, acc[0][3]);
      acc[1][0] = fmaf(wv.y, xv.x, acc[1][0]); acc[1][1] = fmaf(wv.y, xv.y, acc[1][1]);
      acc[1][2] = fmaf(wv.y, xv.z, acc[1][2]); acc[1][3] = fmaf(wv.y, xv.w, acc[1][3]);
      acc[2][0] = fmaf(wv.z, xv.x, acc[2][0]); acc[2][1] = fmaf(wv.z, xv.y, acc[2][1]);
      acc[2][2] = fmaf(wv.z, xv.z, acc[2][2]); acc[2][3] = fmaf(wv.z, xv.w, acc[2][3]);
      acc[3][0] = fmaf(wv.w, xv.x, acc[3][0]); acc[3][1] = fmaf(wv.w, xv.y, acc[3][1]);
      acc[3][2] = fmaf(wv.w, xv.z, acc[3][2]); acc[3][3] = fmaf(wv.w, xv.w, acc[3][3]);
    }
#pragma unroll
    for (int i = 0; i < 4; ++i) {
      l1t[ob + i][pb + 0] = prelu_f(acc[i][0], a);
      l1t[ob + i][pb + 1] = prelu_f(acc[i][1], a);
      l1t[ob + i][pb + 2] = prelu_f(acc[i][2], a);
      l1t[ob + i][pb + 3] = prelu_f(acc[i][3], a);
    }
  }
  __syncthreads();

  // layer 2: (256 + 3 tail) -> 128; thread = 4 outs x 2 points
  {
    const int ob = (t & 31) * 4;
    const int pb = (t >> 5) * 2;
    float acc[4][2];
#pragma unroll
    for (int i = 0; i < 4; ++i) { acc[i][0] = 0.0f; acc[i][1] = 0.0f; }
    for (int c = 0; c < 256; ++c) {
      const float4 wv = *(const float4*)&wT2[c * 128 + ob];
      const float2 xv = *(const float2*)&l1t[c][pb];
      acc[0][0] = fmaf(wv.x, xv.x, acc[0][0]); acc[0][1] = fmaf(wv.x, xv.y, acc[0][1]);
      acc[1][0] = fmaf(wv.y, xv.x, acc[1][0]); acc[1][1] = fmaf(wv.y, xv.y, acc[1][1]);
      acc[2][0] = fmaf(wv.z, xv.x, acc[2][0]); acc[2][1] = fmaf(wv.z, xv.y, acc[2][1]);
      acc[3][0] = fmaf(wv.w, xv.x, acc[3][0]); acc[3][1] = fmaf(wv.w, xv.y, acc[3][1]);
    }
#pragma unroll
    for (int kk = 0; kk < 3; ++kk) {
      const float4 wv = *(const float4*)&wT2[(256 + kk) * 128 + ob];
      const float x0 = xs[256 + kk][pb], x1 = xs[256 + kk][pb + 1];
      acc[0][0] = fmaf(wv.x, x0, acc[0][0]); acc[0][1] = fmaf(wv.x, x1, acc[0][1]);
      acc[1][0] = fmaf(wv.y, x0, acc[1][0]); acc[1][1] = fmaf(wv.y, x1, acc[1][1]);
      acc[2][0] = fmaf(wv.z, x0, acc[2][0]); acc[2][1] = fmaf(wv.z, x1, acc[2][1]);
      acc[3][0] = fmaf(wv.w, x0, acc[3][0]); acc[3][1] = fmaf(wv.w, x1, acc[3][1]);
    }
#pragma unroll
    for (int i = 0; i < 4; ++i) {
      l2t[ob + i][pb + 0] = prelu_f(acc[i][0], a);
      l2t[ob + i][pb + 1] = prelu_f(acc[i][1], a);
    }
  }
  __syncthreads();

  // layer 3: (128 + 3 tail) -> 3
  if (t < 48) {
    const int o3 = t % 3, p = t / 3;
    const float* wr = w3 + o3 * 131;
    float s = 0.0f;
    for (int c = 0; c < 128; ++c) s = fmaf(wr[c], l2t[c][p], s);
#pragma unroll
    for (int kk = 0; kk < 3; ++kk) s = fmaf(wr[128 + kk], xs[256 + kk][p], s);
    const int g = g0 + p;
    out[((g >> 11) * 3 + o3) * 2048 + (g & 2047)] = s;
  }
}

extern "C" void kernel_launch(void* const* d_in, const int* in_sizes, int n_in,
                              void* d_out, int out_size, void* d_ws, size_t ws_size,
                              hipStream_t stream) {
  const float* fine   = (const float*)d_in[0];
  const float* coarse = (const float*)d_in[1];
  const float* w1     = (const float*)d_in[2];
  const float* w2     = (const float*)d_in[3];
  const float* w3     = (const float*)d_in[4];
  const float* pa     = (const float*)d_in[5];
  const int*   ridx   = (const int*)d_in[6];

  float* out  = (float*)d_out;
  float* mask = out + 2 * 3 * 2048;            // f32 elem 12288, byte 49152 (16B aligned)

  char* ws = (char*)d_ws;
  int*      lin_sorted = (int*)ws;                              // 16384 B
  float*    wT1  = (float*)(ws + 16384);                        // 265216 B (259x256 f32)
  float*    wT2  = (float*)(ws + 281600);                       // 132608 B (259x128 f32)
  unsigned* keys = (unsigned*)(ws + 414208);                    // 49152 B (2x6144 u32)
  float*    feat = (float*)(ws + 463360);                       // 4243456 B (4096x259 f32)

  pr_fill_v5<<<512, 256, 0, stream>>>((uint4*)mask);
  pr_wprep_v5<<<389, 256, 0, stream>>>(w1, w2, wT1, wT2);
  pr_uncert_v5<<<48, 256, 0, stream>>>(coarse, ridx, keys);
  pr_topk_v5<<<2, 1024, 0, stream>>>(keys, ridx, lin_sorted, mask);
  pr_gather_v5<<<4096, 256, 0, stream>>>(fine, coarse, lin_sorted, feat);
  pr_mlp_v5<<<256, 256, 0, stream>>>(feat, wT1, wT2, w3, pa, out);
}

// Round 6
// 259.127 us; speedup vs baseline: 1.0064x; 1.0064x over previous
//
#include <hip/hip_runtime.h>
#include <hip/hip_bf16.h>

#define NPTS 2048
#define NOVER 6144
#define STEP1 1536
#define STEP2 512
#define HW_TOT 262144

__device__ __forceinline__ float prelu_f(float x, float a) { return x >= 0.0f ? x : a * x; }

// coarse (128x128) bilinear coords for 512-output half-pixel sampling
__device__ __forceinline__ void coarse_coords(int h, int w, float& fy, float& fx,
                                              int& y0, int& y1, int& x0, int& x1) {
  float sy = (h + 0.5f) * 0.25f - 0.5f;
  float sx = (w + 0.5f) * 0.25f - 0.5f;
  float yf = floorf(sy), xf = floorf(sx);
  fy = sy - yf; fx = sx - xf;
  int yi = (int)yf, xi = (int)xf;
  y0 = min(127, max(0, yi)); y1 = min(127, max(0, yi + 1));
  x0 = min(127, max(0, xi)); x1 = min(127, max(0, xi + 1));
}

__device__ __forceinline__ float coarse_sample(const float* __restrict__ ch, float fy, float fx,
                                               int y0, int y1, int x0, int x1) {
  float v00 = ch[(y0 << 7) + x0];
  float v01 = ch[(y0 << 7) + x1];
  float v10 = ch[(y1 << 7) + x0];
  float v11 = ch[(y1 << 7) + x1];
  return (1.0f - fy) * ((1.0f - fx) * v00 + fx * v01) + fy * ((1.0f - fx) * v10 + fx * v11);
}

// Block-specialized prep: [0,512) zero mask; [512,901) transpose w1/w2; [901,949) uncertainty keys
__global__ __launch_bounds__(256) void pr_prep_v6(const float* __restrict__ w1,
                                                  const float* __restrict__ w2,
                                                  const float* __restrict__ coarse,
                                                  const int* __restrict__ ridx,
                                                  float* __restrict__ wT1,
                                                  float* __restrict__ wT2,
                                                  unsigned* __restrict__ keys,
                                                  uint4* __restrict__ maskv) {
  const int blk = blockIdx.x, t = threadIdx.x;
  if (blk < 512) {
    maskv[blk * 256 + t] = make_uint4(0u, 0u, 0u, 0u);
  } else if (blk < 901) {
    int gid = (blk - 512) * 256 + t;
    if (gid < 259 * 256) {
      int c = gid >> 8, o = gid & 255;
      wT1[c * 256 + o] = w1[o * 259 + c];
    } else {
      int g2 = gid - 259 * 256;
      if (g2 < 259 * 128) {
        int c = g2 >> 7, o = g2 & 127;
        wT2[c * 128 + o] = w2[o * 259 + c];
      }
    }
  } else {
    int gid = (blk - 901) * 256 + t;
    int b = gid / NOVER, i = gid - b * NOVER;
    int lin = ridx[i];
    int h = lin >> 9, w = lin & 511;
    float fy, fx; int y0, y1, x0, x1;
    coarse_coords(h, w, fy, fx, y0, y1, x0, x1);
    const float* cb = coarse + (((size_t)b * 3) << 14);
    float p0 = coarse_sample(cb, fy, fx, y0, y1, x0, x1);
    float p1 = coarse_sample(cb + (1 << 14), fy, fx, y0, y1, x0, x1);
    float p2 = coarse_sample(cb + (2 << 14), fy, fx, y0, y1, x0, x1);
    float m = fmaxf(p0, fmaxf(p1, p2));
    float e0 = expf(p0 - m), e1 = expf(p1 - m), e2 = expf(p2 - m);
    float s = e0 + e1 + e2;
    float q0 = e0 / s, q1 = e1 / s, q2 = e2 / s;
    float a0 = q0, a1 = q1, a2 = q2, tmp;
    if (a0 < a1) { tmp = a0; a0 = a1; a1 = tmp; }
    if (a1 < a2) { tmp = a1; a1 = a2; a2 = tmp; }
    if (a0 < a1) { tmp = a0; a0 = a1; a1 = tmp; }
    float u = 1.0f - (a0 - a1);   // strictly positive -> bit pattern is order-monotone
    keys[gid] = __float_as_uint(u);
  }
}

// One block per batch: exact radix-select top-1536 (val desc, idx asc tie-break),
// mask scatter, and bitmap-based ascending sort of the 2048 selected lins.
__global__ __launch_bounds__(1024) void pr_topk_v6(const unsigned* __restrict__ keys,
                                                   const int* __restrict__ ridx,
                                                   int* __restrict__ lin_sorted,
                                                   float* __restrict__ mask) {
  __shared__ unsigned kv[NOVER];            // 24 KB
  __shared__ unsigned bitmap[8192];         // 32 KB (262144 bits)
  __shared__ unsigned hist[256];
  __shared__ unsigned short tiebuf[NOVER];  // 12 KB (worst-case ties)
  __shared__ unsigned scanbuf[16];
  __shared__ unsigned selinfo[2];           // [0]=prefix/T, [1]=R
  __shared__ int tiecnt;
  const int b = blockIdx.x, t = threadIdx.x;
  const int lane = t & 63, wid = t >> 6;

  for (int i = t; i < NOVER; i += 1024) kv[i] = keys[b * NOVER + i];
  for (int i = t; i < 8192; i += 1024) bitmap[i] = 0u;
  if (t == 0) { selinfo[1] = STEP1; tiecnt = 0; }
  __syncthreads();

  // 4-pass radix select (descending): find exact threshold T and tie-rank r
  unsigned prefix = 0u;
  for (int pass = 0; pass < 4; ++pass) {
    const int shift = 24 - 8 * pass;
    const unsigned maskHi = (pass == 0) ? 0u : (0xFFFFFFFFu << (shift + 8));
    for (int i = t; i < 256; i += 1024) hist[i] = 0u;
    __syncthreads();
    for (int i = t; i < NOVER; i += 1024) {
      unsigned k = kv[i];
      if ((k & maskHi) == prefix) atomicAdd(&hist[(k >> shift) & 255u], 1u);
    }
    __syncthreads();
    if (t < 64) {  // one wave: suffix scan over 256 bins (4 bins/lane)
      unsigned h0 = hist[t * 4], h1 = hist[t * 4 + 1], h2 = hist[t * 4 + 2], h3 = hist[t * 4 + 3];
      unsigned q = h0 + h1 + h2 + h3;
      unsigned s = q;
      for (int off = 1; off < 64; off <<= 1) {
        unsigned n = __shfl_down(s, off);
        if (t + off < 64) s += n;
      }
      unsigned exq = s - q;                    // count in strictly-higher quads
      unsigned R = selinfo[1];                 // lockstep: all lanes read before any write
      unsigned se3 = exq, se2 = se3 + h3, se1 = se2 + h2, se0 = se1 + h1;
      if (se3 < R && R <= se3 + h3)      { selinfo[0] = prefix | ((unsigned)(t * 4 + 3) << shift); selinfo[1] = R - se3; }
      else if (se2 < R && R <= se2 + h2) { selinfo[0] = prefix | ((unsigned)(t * 4 + 2) << shift); selinfo[1] = R - se2; }
      else if (se1 < R && R <= se1 + h1) { selinfo[0] = prefix | ((unsigned)(t * 4 + 1) << shift); selinfo[1] = R - se1; }
      else if (se0 < R && R <= se0 + h0) { selinfo[0] = prefix | ((unsigned)(t * 4 + 0) << shift); selinfo[1] = R - se0; }
    }
    __syncthreads();
    prefix = selinfo[0];
  }
  const unsigned T = prefix;
  const int r = (int)selinfo[1];   // take r smallest-index items among key==T

  // selection pass: key > T definitely in; ties collected
  for (int i = t; i < NOVER; i += 1024) {
    unsigned k = kv[i];
    if (k > T) {
      int lin = ridx[i];
      mask[(size_t)b * HW_TOT + lin] = 1.0f;
      atomicOr(&bitmap[lin >> 5], 1u << (lin & 31));
    } else if (k == T) {
      int pos = atomicAdd(&tiecnt, 1);
      tiebuf[pos] = (unsigned short)i;
    }
  }
  // coverage points (last 512 of the permutation; disjoint from candidates)
  for (int i = t; i < STEP2; i += 1024) {
    int lin = ridx[HW_TOT - STEP2 + i];
    mask[(size_t)b * HW_TOT + lin] = 1.0f;
    atomicOr(&bitmap[lin >> 5], 1u << (lin & 31));
  }
  __syncthreads();
  const int m = tiecnt;
  for (int j = t; j < m; j += 1024) {
    int idx = tiebuf[j];
    int rank = 0;
    for (int jj = 0; jj < m; ++jj) rank += (tiebuf[jj] < idx) ? 1 : 0;
    if (rank < r) {
      int lin = ridx[idx];
      mask[(size_t)b * HW_TOT + lin] = 1.0f;
      atomicOr(&bitmap[lin >> 5], 1u << (lin & 31));
    }
  }
  __syncthreads();

  // bitmap -> ascending lin_sorted via popcount prefix scan (2048 set bits exactly)
  unsigned mySum = 0;
#pragma unroll
  for (int q = 0; q < 8; ++q) mySum += __popc(bitmap[t * 8 + q]);
  unsigned v = mySum;
  for (int off = 1; off < 64; off <<= 1) {
    unsigned n = __shfl_up(v, off);
    if (lane >= off) v += n;
  }
  if (lane == 63) scanbuf[wid] = v;
  __syncthreads();
  if (t == 0) {
    unsigned run = 0;
    for (int w16 = 0; w16 < 16; ++w16) { unsigned tmp = scanbuf[w16]; scanbuf[w16] = run; run += tmp; }
  }
  __syncthreads();
  unsigned pos = (v - mySum) + scanbuf[wid];
  for (int q = 0; q < 8; ++q) {
    unsigned word = bitmap[t * 8 + q];
    int basebit = (t * 8 + q) << 5;
    while (word) {
      int bit = __ffs(word) - 1;
      word &= word - 1;
      lin_sorted[b * NPTS + pos++] = basebit + bit;
    }
  }
}

// Materialize featflat[g*259+c] (reference's flatten-concat-reshape layout) into ws.
__global__ __launch_bounds__(256) void pr_gather_v6(const float* __restrict__ fine,
                                                    const float* __restrict__ coarse,
                                                    const int* __restrict__ lin_sorted,
                                                    float* __restrict__ feat) {
  const int g = blockIdx.x;
  for (int c = threadIdx.x; c < 259; c += 256) {
    int j = g * 259 + c;
    float v;
    if (j < 1048576) {
      int nsrc = j >> 8, ch = j & 255;
      int bs = nsrc >> 11;
      int lin = lin_sorted[nsrc];
      int h = lin >> 9, w = lin & 511;
      float sy = (h + 0.5f) * 0.5f - 0.5f;
      float sx = (w + 0.5f) * 0.5f - 0.5f;
      float yf = floorf(sy), xf = floorf(sx);
      float fy = sy - yf, fx = sx - xf;
      int yi = (int)yf, xi = (int)xf;
      int y0 = min(255, max(0, yi)), y1 = min(255, max(0, yi + 1));
      int x0 = min(255, max(0, xi)), x1 = min(255, max(0, xi + 1));
      const float* base = fine + (((size_t)(bs * 256 + ch)) << 16);
      float v00 = base[(y0 << 8) + x0];
      float v01 = base[(y0 << 8) + x1];
      float v10 = base[(y1 << 8) + x0];
      float v11 = base[(y1 << 8) + x1];
      v = (1.0f - fy) * ((1.0f - fx) * v00 + fx * v01) + fy * ((1.0f - fx) * v10 + fx * v11);
    } else {
      int jj = j - 1048576;
      int nsrc = jj / 3;
      int kk = jj - nsrc * 3;
      int bs = nsrc >> 11;
      int lin = lin_sorted[nsrc];
      int h = lin >> 9, w = lin & 511;
      float fy, fx; int y0, y1, x0, x1;
      coarse_coords(h, w, fy, fx, y0, y1, x0, x1);
      v = coarse_sample(coarse + (((size_t)bs * 3 + kk) << 14), fy, fx, y0, y1, x0, x1);
    }
    feat[j] = v;
  }
}

// 3-layer MLP, 8 points/block (512 blocks = 2/CU). Point-major LDS layouts:
// xs fill = contiguous float4 copy; l1/l2 stores = per-lane contiguous float4
// (conflict-free); activation reads = wave-uniform broadcasts.
__global__ __launch_bounds__(256) void pr_mlp_v6(const float* __restrict__ feat,
                                                 const float* __restrict__ wT1,
                                                 const float* __restrict__ wT2,
                                                 const float* __restrict__ w3,
                                                 const float* __restrict__ pa,
                                                 float* __restrict__ out) {
  __shared__ __align__(16) float xsf[8 * 259];  // xsf[p*259+c]
  __shared__ __align__(16) float l1[8 * 256];   // l1[p*256+o]
  __shared__ __align__(16) float l2[8 * 128];   // l2[p*128+o]
  const int t = threadIdx.x;
  const int g0 = blockIdx.x * 8;
  const float a = pa[0];

  // contiguous copy: 8*259 = 2072 floats = 518 float4 (g0*259 is 16B-aligned: 2072|4)
  {
    const float4* src = (const float4*)(feat + g0 * 259);
    float4* dst = (float4*)xsf;
    for (int i = t; i < 518; i += 256) dst[i] = src[i];
  }
  __syncthreads();

  // layer 1: 259 -> 256; thread = 4 contiguous outs x 2 points
  {
    const int ob = (t & 63) * 4;
    const int pb = (t >> 6) * 2;
    float acc[4][2];
#pragma unroll
    for (int i = 0; i < 4; ++i) { acc[i][0] = 0.0f; acc[i][1] = 0.0f; }
    const float* x0p = xsf + pb * 259;
    const float* x1p = xsf + (pb + 1) * 259;
    for (int c = 0; c < 259; ++c) {
      const float4 wv = *(const float4*)&wT1[c * 256 + ob];  // wave reads 1 KB contiguous
      const float xv0 = x0p[c];                              // LDS broadcast
      const float xv1 = x1p[c];
      acc[0][0] = fmaf(wv.x, xv0, acc[0][0]); acc[0][1] = fmaf(wv.x, xv1, acc[0][1]);
      acc[1][0] = fmaf(wv.y, xv0, acc[1][0]); acc[1][1] = fmaf(wv.y, xv1, acc[1][1]);
      acc[2][0] = fmaf(wv.z, xv0, acc[2][0]); acc[2][1] = fmaf(wv.z, xv1, acc[2][1]);
      acc[3][0] = fmaf(wv.w, xv0, acc[3][0]); acc[3][1] = fmaf(wv.w, xv1, acc[3][1]);
    }
#pragma unroll
    for (int q = 0; q < 2; ++q) {
      float4 r;
      r.x = prelu_f(acc[0][q], a); r.y = prelu_f(acc[1][q], a);
      r.z = prelu_f(acc[2][q], a); r.w = prelu_f(acc[3][q], a);
      *(float4*)&l1[(pb + q) * 256 + ob] = r;   // contiguous per lane -> conflict-free
    }
  }
  __syncthreads();

  // layer 2: (256 + 3 tail) -> 128; thread = 4 contiguous outs x 1 point
  {
    const int ob = (t & 31) * 4;
    const int p = t >> 5;
    float acc[4] = {0.0f, 0.0f, 0.0f, 0.0f};
    const float* xp = l1 + p * 256;
    for (int c = 0; c < 256; ++c) {
      const float4 wv = *(const float4*)&wT2[c * 128 + ob];
      const float xv = xp[c];
      acc[0] = fmaf(wv.x, xv, acc[0]);
      acc[1] = fmaf(wv.y, xv, acc[1]);
      acc[2] = fmaf(wv.z, xv, acc[2]);
      acc[3] = fmaf(wv.w, xv, acc[3]);
    }
#pragma unroll
    for (int kk = 0; kk < 3; ++kk) {
      const float4 wv = *(const float4*)&wT2[(256 + kk) * 128 + ob];
      const float xv = xsf[p * 259 + 256 + kk];
      acc[0] = fmaf(wv.x, xv, acc[0]);
      acc[1] = fmaf(wv.y, xv, acc[1]);
      acc[2] = fmaf(wv.z, xv, acc[2]);
      acc[3] = fmaf(wv.w, xv, acc[3]);
    }
    float4 r;
    r.x = prelu_f(acc[0], a); r.y = prelu_f(acc[1], a);
    r.z = prelu_f(acc[2], a); r.w = prelu_f(acc[3], a);
    *(float4*)&l2[p * 128 + ob] = r;
  }
  __syncthreads();

  // layer 3: (128 + 3 tail) -> 3; 3 outs x 8 points = 24 threads
  if (t < 24) {
    const int o3 = t % 3, p = t / 3;
    const float* wr = w3 + o3 * 131;
    const float* xp = l2 + p * 128;
    float s = 0.0f;
    for (int c = 0; c < 128; ++c) s = fmaf(wr[c], xp[c], s);
#pragma unroll
    for (int kk = 0; kk < 3; ++kk) s = fmaf(wr[128 + kk], xsf[p * 259 + 256 + kk], s);
    const int g = g0 + p;
    out[((g >> 11) * 3 + o3) * 2048 + (g & 2047)] = s;
  }
}

extern "C" void kernel_launch(void* const* d_in, const int* in_sizes, int n_in,
                              void* d_out, int out_size, void* d_ws, size_t ws_size,
                              hipStream_t stream) {
  const float* fine   = (const float*)d_in[0];
  const float* coarse = (const float*)d_in[1];
  const float* w1     = (const float*)d_in[2];
  const float* w2     = (const float*)d_in[3];
  const float* w3     = (const float*)d_in[4];
  const float* pa     = (const float*)d_in[5];
  const int*   ridx   = (const int*)d_in[6];

  float* out  = (float*)d_out;
  float* mask = out + 2 * 3 * 2048;            // f32 elem 12288, byte 49152 (16B aligned)

  char* ws = (char*)d_ws;
  int*      lin_sorted = (int*)ws;                              // 16384 B
  float*    wT1  = (float*)(ws + 16384);                        // 265216 B (259x256 f32)
  float*    wT2  = (float*)(ws + 281600);                       // 132608 B (259x128 f32)
  unsigned* keys = (unsigned*)(ws + 414208);                    // 49152 B (2x6144 u32)
  float*    feat = (float*)(ws + 463360);                       // 4243456 B (4096x259 f32)

  pr_prep_v6<<<949, 256, 0, stream>>>(w1, w2, coarse, ridx, wT1, wT2, keys, (uint4*)mask);
  pr_topk_v6<<<2, 1024, 0, stream>>>(keys, ridx, lin_sorted, mask);
  pr_gather_v6<<<4096, 256, 0, stream>>>(fine, coarse, lin_sorted, feat);
  pr_mlp_v6<<<512, 256, 0, stream>>>(feat, wT1, wT2, w3, pa, out);
}